// Round 4
// baseline (2047.493 us; speedup 1.0000x reference)
//
#include <hip/hip_runtime.h>
#include <stdint.h>
#include <stddef.h>

#define DIM    1024
#define NBATCH 8
#define SEQL   2048
#define JSUM   512
#define SPMAX  2304

typedef unsigned long long ull;
typedef __attribute__((ext_vector_type(8))) __bf16 bf16x8;
typedef __attribute__((ext_vector_type(8))) short  short8;
typedef __attribute__((ext_vector_type(4))) float  floatx4;

__device__ __forceinline__ short f2bf(float f) {
  unsigned u = __builtin_bit_cast(unsigned, f);
  u = (u + 0x7fffu + ((u >> 16) & 1u)) >> 16;   // RNE
  return (short)u;
}
__device__ __forceinline__ float bf2f(short s) {
  unsigned u = ((unsigned)(unsigned short)s) << 16;
  return __builtin_bit_cast(float, u);
}

// NOTE: the intrinsic's imm-offset arg applies to BOTH global and LDS
// addresses — always pass 0 and do pointer arithmetic on both sides.
__device__ __forceinline__ void glds16(const short* g, short8* l) {
  __builtin_amdgcn_global_load_lds(
      (const __attribute__((address_space(1))) unsigned int*)g,
      (__attribute__((address_space(3))) unsigned int*)l, 16, 0, 0);
}

// Counted vmcnt wait (T4): never drain to 0 inside the K-loop.
#define VMCNT(n) do { asm volatile("s_waitcnt vmcnt(" #n ")" ::: "memory"); \
                      __builtin_amdgcn_sched_barrier(0); } while (0)

// Raw barrier WITHOUT the implicit s_waitcnt vmcnt(0) of __syncthreads().
__device__ __forceinline__ void barrier_raw() {
  asm volatile("" ::: "memory");
  __builtin_amdgcn_s_barrier();
  asm volatile("" ::: "memory");
}

// ---------------------------------------------------------------------------
// NT GEMM: C[m,n] = sum_k A[m,k]*B[n,k]. A: M x K row-major, B: N x K row-major.
// 256x128 tile, BK=32, 512 threads (8 waves as 4M x 2N, per-wave 64x64).
// LDS: 3-buffer ring (A 3x16KB + B 3x8KB = 72 KB -> 2 blocks/CU), stage
// distance 2, ONE raw barrier + one counted vmcnt(3) per K-tile.
//   ring safety: reads(t) use buf t%3; DMA(t+2) targets (t+2)%3=(t-1)%3 whose
//   readers finished before barrier(t-1) < issue; vmcnt(3)+barrier at end of
//   iter t-1 guarantees tile t landed + visible before any wave reads it.
// Requires M%256==0, N%128==0, K%32==0, K>=64.
// MODE 0: C bf16            MODE 1: C bf16 + bias[n]
// MODE 2: C bf16 + bias[m]  MODE 3: f32 scatter rows (+bias[n])
// SWIZ 1: gridDim.z==8; batch = lin&7 pins batch->XCD (x = N-tiles, y = M-tiles)
// SWIZ 2: tm=blockIdx.x, tn=blockIdx.y, bz=0 — A-panel sharers on one XCD
//         when gridDim.x % 8 == 0.
// LDS fragment-major: A slot (k8,row) at k8*256+row (k8 0..3); B at k8*128+row.
// Measured conflict-free (SQ_LDS_BANK_CONFLICT = 0 in R0-R3).
// ---------------------------------------------------------------------------
template<int MODE, int SWIZ>
__global__ __launch_bounds__(512, 4)
void gemm_nt(const short* __restrict__ A, ull sA,
             const short* __restrict__ Bm, ull sB,
             short* __restrict__ Cb, ull sC,
             int N, int Kd,
             const float* __restrict__ bias,
             float* __restrict__ dst0, int t_lo, int t_hi, int outT,
             float* __restrict__ dstSp, int t_sp, int Spad)
{
  int tn, tm, bz;
  if (SWIZ == 1) {
    const unsigned gx = gridDim.x;
    ull lin = blockIdx.x + (ull)gx * (blockIdx.y + (ull)gridDim.y * blockIdx.z);
    bz = (int)(lin & 7);
    ull s = lin >> 3;
    tn = (int)(s % gx);
    tm = (int)(s / gx);
  } else {            // SWIZ == 2
    tm = blockIdx.x; tn = blockIdx.y; bz = 0;
  }

  A  += (ull)bz * sA;
  Bm += (ull)bz * sB;

  const int tid  = threadIdx.x;          // 0..511
  const int wave = tid >> 6, lane = tid & 63;

  __shared__ short8 ldsA[3][1024];   // 3 x 16 KB: slot = k8*256 + row
  __shared__ short8 ldsB[3][512];    // 3 x  8 KB: slot = k8*128 + row

  // Staging (3 glds / thread / K-tile):
  //  A slots {tid, tid+512}: row = tid&255, k8 = tid>>8 (+2 for the second)
  //  B slot  {tid}:          row = tid&127, k8 = tid>>7
  const int rA = tid & 255;
  const int rB = tid & 127;
  const short* gA = A  + (long long)(tm * 256 + rA) * Kd + (tid >> 8) * 8;
  const short* gB = Bm + (long long)(tn * 128 + rB) * Kd + (tid >> 7) * 8;

  floatx4 acc[4][4];
#pragma unroll
  for (int i = 0; i < 4; i++)
#pragma unroll
    for (int j = 0; j < 4; j++) acc[i][j] = (floatx4)(0.0f);

  const int wm = (wave >> 1) * 64;   // 4 M-wave rows of 64
  const int wn = (wave & 1) * 64;    // 2 N-wave cols of 64
  const int fr = lane & 15;          // fragment row/col select
  const int fq = lane >> 4;          // k8 select (0..3) within the 32-K tile

  const int nt = Kd >> 5;

  // Issue one K-tile's staging into ring buffer b, advance global pointers.
  auto issue = [&](int b) {
    glds16(gA,      &ldsA[b][wave * 64]);
    glds16(gA + 16, &ldsA[b][wave * 64 + 512]);
    glds16(gB,      &ldsB[b][wave * 64]);
    gA += 32; gB += 32;
  };

  issue(0);            // 3 outstanding
  issue(1);            // 6 outstanding
  VMCNT(3);            // tile 0 landed (tile 1's 3 still in flight)
  barrier_raw();

  int rb = 0, sb = 2;  // read buffer (tile t), stage buffer (tile t+2)
  for (int t = 0; t < nt; t++) {
    const short8* LA = ldsA[rb];
    const short8* LB = ldsB[rb];

    bf16x8 af[4], bv4[4];
    const int aoff = fq * 256 + wm + fr;
    const int boff = fq * 128 + wn + fr;
#pragma unroll
    for (int mt = 0; mt < 4; mt++)
      af[mt] = __builtin_bit_cast(bf16x8, LA[aoff + mt * 16]);
#pragma unroll
    for (int nt2 = 0; nt2 < 4; nt2++)
      bv4[nt2] = __builtin_bit_cast(bf16x8, LB[boff + nt2 * 16]);

    __builtin_amdgcn_s_setprio(1);
#pragma unroll
    for (int mt = 0; mt < 4; mt++)
#pragma unroll
      for (int nt2 = 0; nt2 < 4; nt2++)
        acc[mt][nt2] = __builtin_amdgcn_mfma_f32_16x16x32_bf16(
            af[mt], bv4[nt2], acc[mt][nt2], 0, 0, 0);
    __builtin_amdgcn_s_setprio(0);

    if (t + 2 < nt)      { issue(sb); VMCNT(3); }  // wait = t+1's loads only
    else if (t + 1 < nt) { VMCNT(0); }             // drain final tile
    barrier_raw();                                 // tile t+1 ready for all

    rb = (rb == 2) ? 0 : rb + 1;
    sb = (sb == 2) ? 0 : sb + 1;
  }

  // Epilogue.  C/D layout: col = lane&15, row = (lane>>4)*4 + reg  [m89]
  if (MODE == 3) {
#pragma unroll
    for (int mt = 0; mt < 4; mt++) {
#pragma unroll
      for (int nt2 = 0; nt2 < 4; nt2++) {
        const int col = tn * 128 + wn + nt2 * 16 + fr;
#pragma unroll
        for (int r = 0; r < 4; r++) {
          const int row = tm * 256 + wm + mt * 16 + fq * 4 + r;
          float v = acc[mt][nt2][r] + bias[col];
          int b = row / Spad;
          int tt = row - b * Spad;
          if (tt >= t_lo && tt < t_hi)
            dst0[((size_t)b * outT + (tt - t_lo)) * DIM + col] = v;
          else if (tt == t_sp)
            dstSp[(size_t)b * DIM + col] = v;
        }
      }
    }
  } else {
    short* C = Cb + (ull)bz * sC;
#pragma unroll
    for (int mt = 0; mt < 4; mt++) {
#pragma unroll
      for (int nt2 = 0; nt2 < 4; nt2++) {
        const int col = tn * 128 + wn + nt2 * 16 + fr;
        float bn = (MODE == 1) ? bias[col] : 0.0f;
#pragma unroll
        for (int r = 0; r < 4; r++) {
          const int row = tm * 256 + wm + mt * 16 + fq * 4 + r;
          float v = acc[mt][nt2][r] + bn;
          if (MODE == 2) v += bias[row];
          C[(size_t)row * N + col] = f2bf(v);
        }
      }
    }
  }
}

// ---------------------------------------------------------------------------
// In-place row softmax over bf16 score rows. Row length Spad, valid k < S.
// ---------------------------------------------------------------------------
__global__ __launch_bounds__(256)
void softmax_rows(short* __restrict__ SA, int Spad, int S, float scale)
{
  __shared__ float buf[SPMAX];
  __shared__ float red[8];
  const int t = blockIdx.x, b = blockIdx.y;
  short* row = SA + ((size_t)b * Spad + t) * Spad;
  const int tid = threadIdx.x;

  float mx = -1e30f;
  for (int i = tid; i < S; i += 256) {
    float v = bf2f(row[i]) * scale;
    buf[i] = v;
    mx = fmaxf(mx, v);
  }
  for (int off = 32; off; off >>= 1) mx = fmaxf(mx, __shfl_down(mx, off, 64));
  if ((tid & 63) == 0) red[tid >> 6] = mx;
  __syncthreads();
  if (tid == 0) {
    float m = red[0];
    for (int w = 1; w < 4; w++) m = fmaxf(m, red[w]);
    red[0] = m;
  }
  __syncthreads();
  mx = red[0];

  float sum = 0.f;
  for (int i = tid; i < S; i += 256) {
    float e = __expf(buf[i] - mx);
    buf[i] = e;
    sum += e;
  }
  for (int off = 32; off; off >>= 1) sum += __shfl_down(sum, off, 64);
  if ((tid & 63) == 0) red[4 + (tid >> 6)] = sum;
  __syncthreads();
  if (tid == 0) red[4] = 1.0f / (red[4] + red[5] + red[6] + red[7]);
  __syncthreads();
  const float rinv = red[4];

  for (int i = tid; i < S; i += 256) row[i] = f2bf(buf[i] * rinv);
  for (int i = S + tid; i < Spad; i += 256) row[i] = 0;
}

// ---------------------------------------------------------------------------
__global__ __launch_bounds__(256)
void wtrans(const float* __restrict__ W, short* __restrict__ WT)
{
  __shared__ float tile[32][33];
  const int bn = blockIdx.x * 32, bk = blockIdx.y * 32;
  const int tx = threadIdx.x & 31, ty = threadIdx.x >> 5;  // 32 x 8
#pragma unroll
  for (int j = 0; j < 4; j++)
    tile[ty + j * 8][tx] = W[(size_t)(bk + ty + j * 8) * DIM + bn + tx];
  __syncthreads();
#pragma unroll
  for (int j = 0; j < 4; j++)
    WT[(size_t)(bn + ty + j * 8) * DIM + bk + tx] = f2bf(tile[tx][ty + j * 8]);
}

// ---------------------------------------------------------------------------
__global__ __launch_bounds__(256)
void assemble0(const float* __restrict__ seg0, short* __restrict__ X)
{
  const int Spad = SPMAX;
  const int b = blockIdx.y;
  const size_t lin = ((size_t)blockIdx.x * 256 + threadIdx.x) * 4;
  const int t = (int)(lin >> 10), d = (int)(lin & 1023);
  float4 v = make_float4(0.f, 0.f, 0.f, 0.f);
  if (t >= 1 && t <= SEQL)
    v = *(const float4*)(seg0 + ((size_t)b * SEQL + (t - 1)) * DIM + d);
  union { short s[4]; ull u; } o;
  o.s[0] = f2bf(v.x); o.s[1] = f2bf(v.y); o.s[2] = f2bf(v.z); o.s[3] = f2bf(v.w);
  *(ull*)(X + (size_t)b * Spad * DIM + lin) = o.u;
}

__global__ __launch_bounds__(256)
void assembleS(const float* __restrict__ seg1, const float* __restrict__ prompt,
               short* __restrict__ X)
{
  const int Spad = 768;
  const int b = blockIdx.y;
  const size_t lin = ((size_t)blockIdx.x * 256 + threadIdx.x) * 4;
  const int t = (int)(lin >> 10), d = (int)(lin & 1023);
  float4 v = make_float4(0.f, 0.f, 0.f, 0.f);
  if (t == 0 || t == JSUM + 1)
    v = *(const float4*)(prompt + d);
  else if (t >= 1 && t <= JSUM)
    v = *(const float4*)(seg1 + ((size_t)b * SEQL + (t - 1)) * DIM + d);
  union { short s[4]; ull u; } o;
  o.s[0] = f2bf(v.x); o.s[1] = f2bf(v.y); o.s[2] = f2bf(v.z); o.s[3] = f2bf(v.w);
  *(ull*)(X + (size_t)b * Spad * DIM + lin) = o.u;
}

__global__ __launch_bounds__(256)
void assemble1(const float* __restrict__ seg0, const float* __restrict__ seg1,
               const float* __restrict__ P1, short* __restrict__ X)
{
  const int Spad = SPMAX;
  const int b = blockIdx.y;
  const size_t lin = ((size_t)blockIdx.x * 256 + threadIdx.x) * 4;
  const int t = (int)(lin >> 10), d = (int)(lin & 1023);
  float4 v = make_float4(0.f, 0.f, 0.f, 0.f);
  if (t < 32)
    v = *(const float4*)(seg0 + ((size_t)b * SEQL + (SEQL - 32 + t)) * DIM + d);
  else if (t == 32 || t == 2081)
    v = *(const float4*)(P1 + (size_t)b * DIM + d);
  else if (t >= 33 && t <= 2080)
    v = *(const float4*)(seg1 + ((size_t)b * SEQL + (t - 33)) * DIM + d);
  union { short s[4]; ull u; } o;
  o.s[0] = f2bf(v.x); o.s[1] = f2bf(v.y); o.s[2] = f2bf(v.z); o.s[3] = f2bf(v.w);
  *(ull*)(X + (size_t)b * Spad * DIM + lin) = o.u;
}

// ---------------------------------------------------------------------------
__global__ __launch_bounds__(256)
void mem_proj(const float* __restrict__ Sb, const float* __restrict__ M1,
              const float* __restrict__ Wq_mem, const float* __restrict__ bq_mem,
              const float* __restrict__ Wk_mem, const float* __restrict__ bk_mem,
              float* __restrict__ Qn, float* __restrict__ Kp)
{
  const int n = blockIdx.x * 256 + threadIdx.x;
  const int b = blockIdx.y;
  const int w = blockIdx.z;
  const float* x    = w ? M1 : Sb;
  const float* W    = w ? Wk_mem : Wq_mem;
  const float* bias = w ? bk_mem : bq_mem;
  float* o          = w ? Kp : Qn;
  const float* xr = x + (size_t)b * DIM;
  float s = bias[n];
  for (int k = 0; k < DIM; k++) s += xr[k] * W[(size_t)k * DIM + n];
  o[(size_t)b * DIM + n] = s;
}

__global__ __launch_bounds__(256)
void mem_attn(const float* __restrict__ Qn, const float* __restrict__ Kp,
              const float* __restrict__ M1, float* __restrict__ P1, float scale)
{
  __shared__ float red[256];
  __shared__ float w8[8];
  const int b = blockIdx.x, tid = threadIdx.x;
  for (int bp = 0; bp < NBATCH; bp++) {
    float p = 0.f;
    for (int k = tid; k < DIM; k += 256)
      p += Qn[(size_t)b * DIM + k] * Kp[(size_t)bp * DIM + k];
    red[tid] = p; __syncthreads();
    for (int off = 128; off; off >>= 1) {
      if (tid < off) red[tid] += red[tid + off];
      __syncthreads();
    }
    if (tid == 0) w8[bp] = red[0] * scale;
    __syncthreads();
  }
  if (tid == 0) {
    float m = w8[0];
    for (int i = 1; i < NBATCH; i++) m = fmaxf(m, w8[i]);
    float s = 0.f;
    for (int i = 0; i < NBATCH; i++) { w8[i] = __expf(w8[i] - m); s += w8[i]; }
    for (int i = 0; i < NBATCH; i++) w8[i] /= s;
  }
  __syncthreads();
  for (int d = tid; d < DIM; d += 256) {
    float a = 0.f;
    for (int bp = 0; bp < NBATCH; bp++) a += w8[bp] * M1[(size_t)bp * DIM + d];
    P1[(size_t)b * DIM + d] = a;
  }
}

// ---------------------------------------------------------------------------
extern "C" void kernel_launch(void* const* d_in, const int* in_sizes, int n_in,
                              void* d_out, int out_size, void* d_ws, size_t ws_size,
                              hipStream_t stream)
{
  const float* seg0   = (const float*)d_in[0];
  const float* seg1   = (const float*)d_in[1];
  const float* prompt = (const float*)d_in[2];
  const float* Wq_mem = (const float*)d_in[3];
  const float* bq_mem = (const float*)d_in[4];
  const float* Wk_mem = (const float*)d_in[5];
  const float* bk_mem = (const float*)d_in[6];
  const float* Wq     = (const float*)d_in[7];
  const float* bq     = (const float*)d_in[8];
  const float* Wk     = (const float*)d_in[9];
  const float* bk     = (const float*)d_in[10];
  const float* Wv     = (const float*)d_in[11];
  const float* bv     = (const float*)d_in[12];
  const float* Wo     = (const float*)d_in[13];
  const float* bo     = (const float*)d_in[14];
  float* outp = (float*)d_out;

  const size_t WSZ  = (size_t)DIM * DIM * 2;
  const size_t XSZ  = (size_t)NBATCH * SPMAX * DIM * 2;
  const size_t SASZ = (size_t)NBATCH * SPMAX * SPMAX * 2;
  const size_t VSZ  = (size_t)NBATCH * DIM * 4;

  char* p = (char*)d_ws;
  short* WqT = (short*)p; p += WSZ;
  short* WkT = (short*)p; p += WSZ;
  short* WvT = (short*)p; p += WSZ;
  short* WoT = (short*)p; p += WSZ;
  short* X   = (short*)p; p += XSZ;
  short* Qb  = (short*)p; p += XSZ;
  short* Kb  = (short*)p; p += XSZ;
  short* Vt  = (short*)p; p += XSZ;
  short* Ctx = (short*)p; p += XSZ;
  short* SA  = (short*)p; p += SASZ;
  float* M1b = (float*)p; p += VSZ;
  float* Sb  = (float*)p; p += VSZ;
  float* Qn  = (float*)p; p += VSZ;
  float* Kp  = (float*)p; p += VSZ;
  float* P1  = (float*)p; p += VSZ;

  const float scale = 0.03125f;   // 1/sqrt(1024)
  dim3 blk(256, 1, 1);
  dim3 blkG(512, 1, 1);

  auto run_backbone = [&](int Spad, int S,
                          float* o_dst, int t_lo, int t_hi, int outT,
                          float* o_sp, int t_sp) {
    const int MT = NBATCH * Spad / 256;   // M-tiles for row-stacked GEMMs (%8==0)
    // Q = X Wq^T + bq   (SWIZ=2: tm = bx, A-panel sharers on one XCD)
    gemm_nt<1, 2><<<dim3(MT, DIM / 128, 1), blkG, 0, stream>>>(
        X, 0ULL, WqT, 0ULL, Qb, 0ULL, DIM, DIM, bq,
        nullptr, 0, 0, 0, nullptr, -1, Spad);
    // K = X Wk^T + bk
    gemm_nt<1, 2><<<dim3(MT, DIM / 128, 1), blkG, 0, stream>>>(
        X, 0ULL, WkT, 0ULL, Kb, 0ULL, DIM, DIM, bk,
        nullptr, 0, 0, 0, nullptr, -1, Spad);
    // Vt[b] (D x Spad) = NT(WvT, X_b) + bv[m]   (batch->XCD swizzle)
    gemm_nt<2, 1><<<dim3(Spad / 128, DIM / 256, NBATCH), blkG, 0, stream>>>(
        WvT, 0ULL, X, (ull)Spad * DIM,
        Vt, (ull)DIM * Spad, Spad, DIM, bv,
        nullptr, 0, 0, 0, nullptr, -1, Spad);
    // scores[b] = Q_b K_b^T   (batch->XCD swizzle)
    gemm_nt<0, 1><<<dim3(Spad / 128, Spad / 256, NBATCH), blkG, 0, stream>>>(
        Qb, (ull)Spad * DIM, Kb, (ull)Spad * DIM,
        SA, (ull)Spad * Spad, Spad, DIM, nullptr,
        nullptr, 0, 0, 0, nullptr, -1, Spad);
    softmax_rows<<<dim3(Spad, NBATCH), blk, 0, stream>>>(SA, Spad, S, scale);
    // ctx[b] = attn_b Vt_b^T   (batch->XCD swizzle)
    gemm_nt<0, 1><<<dim3(DIM / 128, Spad / 256, NBATCH), blkG, 0, stream>>>(
        SA, (ull)Spad * Spad, Vt, (ull)DIM * Spad,
        Ctx, (ull)Spad * DIM, DIM, Spad, nullptr,
        nullptr, 0, 0, 0, nullptr, -1, Spad);
    // H = ctx Wo^T + bo, scattered to outputs
    gemm_nt<3, 2><<<dim3(MT, DIM / 128, 1), blkG, 0, stream>>>(
        Ctx, 0ULL, WoT, 0ULL, nullptr, 0ULL, DIM, DIM, bo,
        o_dst, t_lo, t_hi, outT, o_sp, t_sp, Spad);
  };

  wtrans<<<dim3(32, 32), blk, 0, stream>>>(Wq, WqT);
  wtrans<<<dim3(32, 32), blk, 0, stream>>>(Wk, WkT);
  wtrans<<<dim3(32, 32), blk, 0, stream>>>(Wv, WvT);
  wtrans<<<dim3(32, 32), blk, 0, stream>>>(Wo, WoT);

  // Phase 0: backbone([P0, seg0, P0])  S=2050, Spad=2304
  assemble0<<<dim3(SPMAX, NBATCH), blk, 0, stream>>>(seg0, X);
  run_backbone(SPMAX, 2050, outp, 33, 2049, 2016, M1b, 2049);

  // Phase S: summarize(seg1)  S=514, Spad=768
  assembleS<<<dim3(768, NBATCH), blk, 0, stream>>>(seg1, prompt, X);
  run_backbone(768, 514, nullptr, 0, 0, 0, Sb, JSUM);

  // Memory attention (exact f32)
  mem_proj<<<dim3(DIM / 256, NBATCH, 2), blk, 0, stream>>>(
      Sb, M1b, Wq_mem, bq_mem, Wk_mem, bk_mem, Qn, Kp);
  mem_attn<<<dim3(NBATCH), blk, 0, stream>>>(Qn, Kp, M1b, P1, scale);

  // Phase 1: backbone([seg0[-32:], P1, seg1, P1])  S=2082, Spad=2304
  assemble1<<<dim3(SPMAX, NBATCH), blk, 0, stream>>>(seg0, seg1, P1, X);
  run_backbone(SPMAX, 2082, outp + (size_t)NBATCH * 2016 * DIM,
               33, 2081, 2048, nullptr, -1);
}